// Round 9
// baseline (164.861 us; speedup 1.0000x reference)
//
#include <hip/hip_runtime.h>

#define NBATCH 256
#define NCH 30

__device__ __forceinline__ float fast_sqrt(float x) {
    float r;
    asm("v_sqrt_f32 %0, %1" : "=v"(r) : "v"(x));
    return r;
}

// One float4 worth of loss. (sqrt(p)-sqrt(t))^2 == p + t - 2*sqrt(p*t).
__device__ __forceinline__ float quad_term(
    float4 pv, float4 tv, float clo, float chi,
    const float A[4], const float B[4], const bool SQ[4])
{
    float obj_lo = (clo == 1.0f) ? 1.0f : 0.0f;
    float obj_hi = (chi == 1.0f) ? 1.0f : 0.0f;
    float pe[4] = {pv.x, pv.y, pv.z, pv.w};
    float te[4] = {tv.x, tv.y, tv.z, tv.w};
    float acc = 0.0f;
    #pragma unroll
    for (int k = 0; k < 4; ++k) {
        float p = pe[k], t = te[k];
        float dns = p - t;
        float vns = dns * dns;
        float vsq = (p + t) - 2.0f * fast_sqrt(p * t);
        float val = SQ[k] ? vsq : vns;
        float ob  = (k < 2) ? obj_lo : obj_hi;   // valid: only c0==28 straddles,
                                                 // and there k=0,1 are lo-cell, k=2,3 hi-cell;
                                                 // for all other phases chi==clo anyway
        float w   = fmaf(ob, A[k], B[k]);
        acc = fmaf(w, val, acc);
    }
    return acc;
}

// Barrier-free one-shot streaming kernel. Grid ≡ 0 (mod 15) -> 4T ≡ 0 (mod 30):
// channel phase c0 is batch-invariant. UF=2: short dependence chain (2 consume
// waits), latency hidden by block turnover (~46 block-slots/CU). Conf loads:
// one per batch; the hi-cell conf is a sparse exec-masked load for the single
// straddling phase c0==28 (1/15 of lanes), select from clo otherwise.
// w(c, obj) = obj*A + B:  c<4 -> (5,0);  c==4 -> (0.5,0.5);  c>=5 -> (1,0).
__global__ __launch_bounds__(256, 8) void yolo_loss_kernel(
    const float* __restrict__ pred,
    const float* __restrict__ targ,
    float* __restrict__ out,
    int n4)
{
    const int T   = gridDim.x * blockDim.x;     // 11760*256 = 3,010,560
    const int tid = blockIdx.x * blockDim.x + threadIdx.x;

    const int e0    = tid * 4;
    const int c0    = e0 % NCH;                 // even; batch-invariant
    const int cell0 = e0 / NCH;
    const int Flo0  = cell0 * NCH + 4;          // lo-cell conf flat index
    const bool straddle = (c0 == 28);           // only phase that spans 2 cells

    float A[4], B[4];
    bool  SQ[4];
    #pragma unroll
    for (int k = 0; k < 4; ++k) {
        int c = c0 + k; if (c >= NCH) c -= NCH;
        SQ[k] = (c == 2 || c == 3);
        if (c < 4)       { A[k] = 5.0f; B[k] = 0.0f; }
        else if (c == 4) { A[k] = 0.5f; B[k] = 0.5f; }
        else             { A[k] = 1.0f; B[k] = 0.0f; }
    }

    const float4* __restrict__ p4 = reinterpret_cast<const float4*>(pred);
    const float4* __restrict__ t4 = reinterpret_cast<const float4*>(targ);

    float acc = 0.0f;

    if (n4 == 2 * T) {
        // ---------- fast path (shipped shape): UF=2, all loads up front ----------
        const int T4 = 4 * T;                   // conf flat-offset per batch
        float4 pv0 = p4[tid];
        float4 tv0 = t4[tid];
        float4 pv1 = p4[tid + T];
        float4 tv1 = t4[tid + T];
        float clo0 = targ[Flo0];
        float clo1 = targ[Flo0 + T4];
        float chi0 = clo0, chi1 = clo1;
        if (straddle) {                         // sparse masked loads (1/15 lanes)
            chi0 = targ[Flo0 + NCH];
            chi1 = targ[Flo0 + NCH + T4];
        }
        acc += quad_term(pv0, tv0, clo0, chi0, A, B, SQ);
        acc += quad_term(pv1, tv1, clo1, chi1, A, B, SQ);
    } else {
        // ---------- generic fallback (any n4; grid always mult of 15) ----------
        const int T4 = 4 * T;
        int m = 0;
        for (int i = tid; i < n4; i += T, ++m) {
            float4 pv = p4[i];
            float4 tv = t4[i];
            float clo = targ[Flo0 + m * T4];
            float chi = straddle ? targ[Flo0 + NCH + m * T4] : clo;
            acc += quad_term(pv, tv, clo, chi, A, B, SQ);
        }
    }

    // wave64 shuffle reduction -> block LDS -> one atomic per block
    #pragma unroll
    for (int off = 32; off > 0; off >>= 1)
        acc += __shfl_down(acc, off, 64);

    __shared__ float lds[4];
    int lane = threadIdx.x & 63;
    int wid  = threadIdx.x >> 6;
    if (lane == 0) lds[wid] = acc;
    __syncthreads();
    if (threadIdx.x == 0) {
        float s = lds[0] + lds[1] + lds[2] + lds[3];
        atomicAdd(out, s * (1.0f / (float)NBATCH));
    }
}

extern "C" void kernel_launch(void* const* d_in, const int* in_sizes, int n_in,
                              void* d_out, int out_size, void* d_ws, size_t ws_size,
                              hipStream_t stream)
{
    const float* pred = (const float*)d_in[0];
    const float* targ = (const float*)d_in[1];
    float* out = (float*)d_out;

    hipMemsetAsync(out, 0, sizeof(float), stream);

    int n  = in_sizes[0];   // 24,084,480
    int n4 = n / 4;         // 6,021,120

    // 11760 ≡ 0 (mod 15): batch-invariant channel phase; 2 float4/thread exactly.
    int blocks = 11760;
    yolo_loss_kernel<<<blocks, 256, 0, stream>>>(pred, targ, out, n4);
}

// Round 10
// 38.941 us; speedup vs baseline: 4.2336x; 4.2336x over previous
//
#include <hip/hip_runtime.h>

#define NBATCH 256
#define NCH 30

__device__ __forceinline__ float fast_sqrt(float x) {
    float r;
    asm("v_sqrt_f32 %0, %1" : "=v"(r) : "v"(x));
    return r;
}

// One float4 worth of loss. (sqrt(p)-sqrt(t))^2 == p + t - 2*sqrt(p*t).
// obj selection: only phase c0==28 straddles two cells, and there k=0,1 are
// lo-cell channels {28,29} and k=2,3 are hi-cell {0,1}; all other phases have
// chi==clo, so (k<2 ? obj_lo : obj_hi) is exact for every phase.
__device__ __forceinline__ float quad_term(
    float4 pv, float4 tv, float clo, float chi,
    const float A[4], const float B[4], const bool SQ[4])
{
    float obj_lo = (clo == 1.0f) ? 1.0f : 0.0f;
    float obj_hi = (chi == 1.0f) ? 1.0f : 0.0f;
    float pe[4] = {pv.x, pv.y, pv.z, pv.w};
    float te[4] = {tv.x, tv.y, tv.z, tv.w};
    float acc = 0.0f;
    #pragma unroll
    for (int k = 0; k < 4; ++k) {
        float p = pe[k], t = te[k];
        float dns = p - t;
        float vns = dns * dns;
        float vsq = (p + t) - 2.0f * fast_sqrt(p * t);
        float val = SQ[k] ? vsq : vns;
        float ob  = (k < 2) ? obj_lo : obj_hi;
        float w   = fmaf(ob, A[k], B[k]);
        acc = fmaf(w, val, acc);
    }
    return acc;
}

// Barrier-free one-shot streaming kernel, R5 structure. Grid ≡ 0 (mod 15) ->
// channel phase c0 is batch-invariant. ALL loads (8 dwordx4 + 4 conf dwords +
// sparse straddle confs) are issued as ONE cluster, then sched_barrier(0)
// fences the consume phase: one vmcnt drain per thread instead of ~3.
// w(c, obj) = obj*A + B:  c<4 -> (5,0);  c==4 -> (0.5,0.5);  c>=5 -> (1,0).
template <bool USE_WS>
__global__ __launch_bounds__(256, 4) void yolo_loss_main_kernel(
    const float* __restrict__ pred,
    const float* __restrict__ targ,
    float* __restrict__ out,        // USE_WS ? per-block partials : atomic target
    int n4)
{
    const int T   = gridDim.x * blockDim.x;     // 5880*256 = 1,505,280
    const int tid = blockIdx.x * blockDim.x + threadIdx.x;

    const int e0    = tid * 4;
    const int c0    = e0 % NCH;                 // even; batch-invariant
    const int cell0 = e0 / NCH;
    const int Flo0  = cell0 * NCH + 4;          // lo-cell conf flat index
    const bool straddle = (c0 == 28);           // only phase spanning 2 cells

    float A[4], B[4];
    bool  SQ[4];
    #pragma unroll
    for (int k = 0; k < 4; ++k) {
        int c = c0 + k; if (c >= NCH) c -= NCH;
        SQ[k] = (c == 2 || c == 3);
        if (c < 4)       { A[k] = 5.0f; B[k] = 0.0f; }
        else if (c == 4) { A[k] = 0.5f; B[k] = 0.5f; }
        else             { A[k] = 1.0f; B[k] = 0.0f; }
    }

    const float4* __restrict__ p4 = reinterpret_cast<const float4*>(pred);
    const float4* __restrict__ t4 = reinterpret_cast<const float4*>(targ);

    float acc = 0.0f;

    if (n4 == 4 * T) {
        // ---------- fast path (shipped shape): UF=4, one load cluster ----------
        const int T4 = 4 * T;                   // conf flat-offset per batch

        float4 pv0 = p4[tid + 0*T], tv0 = t4[tid + 0*T];
        float4 pv1 = p4[tid + 1*T], tv1 = t4[tid + 1*T];
        float4 pv2 = p4[tid + 2*T], tv2 = t4[tid + 2*T];
        float4 pv3 = p4[tid + 3*T], tv3 = t4[tid + 3*T];
        float clo0 = targ[Flo0 + 0*T4];
        float clo1 = targ[Flo0 + 1*T4];
        float clo2 = targ[Flo0 + 2*T4];
        float clo3 = targ[Flo0 + 3*T4];
        float chl0 = 0.f, chl1 = 0.f, chl2 = 0.f, chl3 = 0.f;
        if (straddle) {                         // sparse masked loads (1/15 lanes)
            chl0 = targ[Flo0 + NCH + 0*T4];
            chl1 = targ[Flo0 + NCH + 1*T4];
            chl2 = targ[Flo0 + NCH + 2*T4];
            chl3 = targ[Flo0 + NCH + 3*T4];
        }
        // fence: nothing below may be hoisted between/above the loads
        __builtin_amdgcn_sched_barrier(0);

        float chi0 = straddle ? chl0 : clo0;
        float chi1 = straddle ? chl1 : clo1;
        float chi2 = straddle ? chl2 : clo2;
        float chi3 = straddle ? chl3 : clo3;

        acc += quad_term(pv0, tv0, clo0, chi0, A, B, SQ);
        acc += quad_term(pv1, tv1, clo1, chi1, A, B, SQ);
        acc += quad_term(pv2, tv2, clo2, chi2, A, B, SQ);
        acc += quad_term(pv3, tv3, clo3, chi3, A, B, SQ);
    } else {
        // ---------- generic fallback (any n4; grid always mult of 15) ----------
        const int T4 = 4 * T;
        int m = 0;
        for (int i = tid; i < n4; i += T, ++m) {
            float4 pv = p4[i];
            float4 tv = t4[i];
            float clo = targ[Flo0 + m * T4];
            float chi = straddle ? targ[Flo0 + NCH + m * T4] : clo;
            acc += quad_term(pv, tv, clo, chi, A, B, SQ);
        }
    }

    // wave64 shuffle reduction -> block LDS -> partial store / atomic
    #pragma unroll
    for (int off = 32; off > 0; off >>= 1)
        acc += __shfl_down(acc, off, 64);

    __shared__ float lds[4];
    int lane = threadIdx.x & 63;
    int wid  = threadIdx.x >> 6;
    if (lane == 0) lds[wid] = acc;
    __syncthreads();
    if (threadIdx.x == 0) {
        float s = lds[0] + lds[1] + lds[2] + lds[3];
        if (USE_WS) out[blockIdx.x] = s;
        else        atomicAdd(out, s * (1.0f / (float)NBATCH));
    }
}

// Sum nblocks partials -> out[0], fold the 1/NBATCH.
__global__ __launch_bounds__(256) void yolo_loss_finish_kernel(
    const float* __restrict__ partial, float* __restrict__ out, int n)
{
    float acc = 0.0f;
    for (int i = threadIdx.x; i < n; i += 256) acc += partial[i];
    #pragma unroll
    for (int off = 32; off > 0; off >>= 1)
        acc += __shfl_down(acc, off, 64);
    __shared__ float lds[4];
    int lane = threadIdx.x & 63, wid = threadIdx.x >> 6;
    if (lane == 0) lds[wid] = acc;
    __syncthreads();
    if (threadIdx.x == 0)
        out[0] = (lds[0] + lds[1] + lds[2] + lds[3]) * (1.0f / (float)NBATCH);
}

extern "C" void kernel_launch(void* const* d_in, const int* in_sizes, int n_in,
                              void* d_out, int out_size, void* d_ws, size_t ws_size,
                              hipStream_t stream)
{
    const float* pred = (const float*)d_in[0];
    const float* targ = (const float*)d_in[1];
    float* out = (float*)d_out;

    int n  = in_sizes[0];   // 24,084,480
    int n4 = n / 4;         // 6,021,120

    // 5880 ≡ 0 (mod 15): batch-invariant channel phase; 4 float4/thread exactly.
    int blocks = 5880;

    if (ws_size >= (size_t)blocks * sizeof(float)) {
        float* partial = (float*)d_ws;
        yolo_loss_main_kernel<true><<<blocks, 256, 0, stream>>>(pred, targ, partial, n4);
        yolo_loss_finish_kernel<<<1, 256, 0, stream>>>(partial, out, blocks);
    } else {
        hipMemsetAsync(out, 0, sizeof(float), stream);
        yolo_loss_main_kernel<false><<<blocks, 256, 0, stream>>>(pred, targ, out, n4);
    }
}